// Round 10
// baseline (2278.460 us; speedup 1.0000x reference)
//
#include <hip/hip_runtime.h>
#include <hip/hip_bf16.h>

constexpr int DIN = 16;
constexpr int D   = 256;
constexpr int NH  = 8;
constexpr int NC  = 32;
constexpr int MC  = 200;
constexpr int NT  = 8;
constexpr int BG  = 16;
constexpr int NL  = 6;
constexpr int PS  = 16;    // pool slices per graph
constexpr int NB  = 512;   // persistent grid: 2 blocks/CU, co-resident via __launch_bounds__(256,2)
constexpr float NEG = 0.2f;

typedef __attribute__((ext_vector_type(8))) short bfrag;
typedef __attribute__((ext_vector_type(4))) float f32x4;

__device__ inline unsigned short f2bf(float f) {
    unsigned int u = __float_as_uint(f);
    u += 0x7FFFu + ((u >> 16) & 1u);
    return (unsigned short)(u >> 16);
}
__device__ inline float bf2f(unsigned short u) {
    return __uint_as_float((unsigned int)u << 16);
}

union ShMem {
    struct { unsigned short As[16][264]; unsigned short Zs[16][264]; } mm;  // 16896 B
    struct { float g[2 * D]; float z1[D]; float z2[128]; } hd;
    int scan[256];
};

__device__ inline float dot_ilp(const float* g, const float* __restrict__ W, int K, int ldw, int t) {
    float a0 = 0.f, a1 = 0.f, a2 = 0.f, a3 = 0.f;
    for (int k = 0; k < K; k += 4) {
        a0 = fmaf(g[k + 0], W[(k + 0) * ldw + t], a0);
        a1 = fmaf(g[k + 1], W[(k + 1) * ldw + t], a1);
        a2 = fmaf(g[k + 2], W[(k + 2) * ldw + t], a2);
        a3 = fmaf(g[k + 3], W[(k + 3) * ldw + t], a3);
    }
    return (a0 + a1) + (a2 + a3);
}

struct MegaArgs {
    const float *x; const int *esrc, *edst, *batch;
    const float *encW, *encb, *encls, *enclb;
    const float *Wl, *bl, *Wr, *br, *att, *gb, *gls, *glb;
    const float *cW1, *cb1, *cW2, *cb2, *cW3, *cb3;
    const float *chW1, *chb1, *chW2, *chb2, *chW3, *chb3;
    const float *tW1, *tb1, *tW2, *tb2, *dW1, *db1, *dW2, *db2;
    int *row_ptr, *fill, *deg, *cnt, *part, *part2;
    float *psum, *pmax;
    int *col;
    unsigned short *Wp, *cW1p, *cW2p, *cW3p;
    float *h; unsigned short *xl, *xr;
    float *out_colors, *out_ch, *out_t, *out_d;
    unsigned *bar;
    int N, E;
};

// ---------------------------------------------------------------- phase bodies

__device__ inline void repack_attn_one(const float* Wl, const float* Wr, unsigned short* Wp, int tid) {
    int lane = tid & 63;
    int r1 = tid >> 6;
    int ks = r1 & 7;
    int r2 = r1 >> 3;
    int ct = r2 & 15;
    int mi = r2 >> 4;
    int layer = mi >> 1, mat = mi & 1;
    const float* W = (mat == 0 ? Wl : Wr) + (size_t)layer * D * D;
    int n = ct * 16 + (lane & 15);
    int kb = ks * 32 + (lane >> 4) * 8;
    size_t base = (((size_t)(mi * 16 + ct) * 8 + ks) * 64 + lane) * 8;
#pragma unroll
    for (int j = 0; j < 8; j++) Wp[base + j] = f2bf(W[(size_t)(kb + j) * D + n]);
}

__device__ inline void repack_gen_one(const float* W, unsigned short* Wp, int K, int NCOL, int nks, int tid) {
    int lane = tid & 63;
    int r = tid >> 6;
    int ks = r % nks;
    int ct = r / nks;
    int n = ct * 16 + (lane & 15);
    int kb = ks * 32 + (lane >> 4) * 8;
    size_t base = (((size_t)ct * nks + ks) * 64 + lane) * 8;
#pragma unroll
    for (int j = 0; j < 8; j++) {
        int k = kb + j;
        Wp[base + j] = (n < NCOL && k < K) ? f2bf(W[(size_t)k * NCOL + n]) : (unsigned short)0;
    }
}

__device__ inline void enc_node(const float* x, const float* W, const float* b, const float* ls,
                                const float* lb, float* h, int n, int lane) {
    int c4 = lane * 4;
    float xs[DIN];
#pragma unroll
    for (int k = 0; k < DIN; k += 4) {
        float4 xv = *(const float4*)&x[n * DIN + k];
        xs[k] = xv.x; xs[k + 1] = xv.y; xs[k + 2] = xv.z; xs[k + 3] = xv.w;
    }
    float4 a = *(const float4*)&b[c4];
#pragma unroll
    for (int k = 0; k < DIN; k++) {
        float4 wv = *(const float4*)&W[k * D + c4];
        a.x = fmaf(xs[k], wv.x, a.x);
        a.y = fmaf(xs[k], wv.y, a.y);
        a.z = fmaf(xs[k], wv.z, a.z);
        a.w = fmaf(xs[k], wv.w, a.w);
    }
    float s = a.x + a.y + a.z + a.w;
#pragma unroll
    for (int msk = 1; msk <= 32; msk <<= 1) s += __shfl_xor(s, msk);
    float mu = s * (1.f / D);
    float4 dv = make_float4(a.x - mu, a.y - mu, a.z - mu, a.w - mu);
    float v2 = dv.x * dv.x + dv.y * dv.y + dv.z * dv.z + dv.w * dv.w;
#pragma unroll
    for (int msk = 1; msk <= 32; msk <<= 1) v2 += __shfl_xor(v2, msk);
    float rstd = rsqrtf(v2 * (1.f / D) + 1e-5f);
    float4 lsv = *(const float4*)&ls[c4];
    float4 lbv = *(const float4*)&lb[c4];
    float4 y = make_float4(fmaxf(dv.x * rstd * lsv.x + lbv.x, 0.f),
                           fmaxf(dv.y * rstd * lsv.y + lbv.y, 0.f),
                           fmaxf(dv.z * rstd * lsv.z + lbv.z, 0.f),
                           fmaxf(dv.w * rstd * lsv.w + lbv.w, 0.f));
    *(float4*)&h[(size_t)n * D + c4] = y;
}

__device__ inline void gemm_tile(const float* h, const unsigned short* WpL, const unsigned short* WpR,
                                 const float* bl, const float* br, unsigned short* xl, unsigned short* xr,
                                 int N, int tt, int T, unsigned short (*As)[264]) {
    int lane = T & 63, w = T >> 6;
    int nb = tt * 16;
#pragma unroll
    for (int r = 0; r < 16; r++) {
        int row = nb + r;
        float v = (row < N) ? h[(size_t)row * D + T] : 0.f;
        As[r][T] = f2bf(v);
    }
    __syncthreads();
    int m = lane & 15;
    int q = lane >> 4;
    int ctbase = w * 4;
    f32x4 accL[4], accR[4];
#pragma unroll
    for (int ct = 0; ct < 4; ct++) {
        float bLv = bl[(ctbase + ct) * 16 + m];
        float bRv = br[(ctbase + ct) * 16 + m];
        accL[ct] = (f32x4){bLv, bLv, bLv, bLv};
        accR[ct] = (f32x4){bRv, bRv, bRv, bRv};
    }
#pragma unroll 2
    for (int ks = 0; ks < 8; ks++) {
        bfrag af = *(const bfrag*)&As[m][ks * 32 + q * 8];
#pragma unroll
        for (int ct = 0; ct < 4; ct++) {
            int ctg = ctbase + ct;
            size_t off = (((size_t)ctg * 8 + ks) * 64 + lane) * 8;
            bfrag bL = *(const bfrag*)&WpL[off];
            bfrag bR = *(const bfrag*)&WpR[off];
            accL[ct] = __builtin_amdgcn_mfma_f32_16x16x32_bf16(af, bL, accL[ct], 0, 0, 0);
            accR[ct] = __builtin_amdgcn_mfma_f32_16x16x32_bf16(af, bR, accR[ct], 0, 0, 0);
        }
    }
#pragma unroll
    for (int ct = 0; ct < 4; ct++) {
        int colg = (ctbase + ct) * 16 + m;
#pragma unroll
        for (int reg = 0; reg < 4; reg++) {
            int row = nb + q * 4 + reg;
            if (row < N) {
                xl[(size_t)row * D + colg] = f2bf(accL[ct][reg]);
                xr[(size_t)row * D + colg] = f2bf(accR[ct][reg]);
            }
        }
    }
}

__device__ inline void attn_node(const unsigned short* xl, const unsigned short* xr,
                                 const int* row_ptr, const int* col, const float* att,
                                 const float* gb, const float* gls, const float* glb,
                                 float* h, int layer, int n, int lane) {
    int c4 = lane * 4;
    ushort4 xr4 = *(const ushort4*)&xr[(size_t)n * D + c4];
    float4 xrv = make_float4(bf2f(xr4.x), bf2f(xr4.y), bf2f(xr4.z), bf2f(xr4.w));
    float4 av  = *(const float4*)&att[c4];
    int beg = row_ptr[n], end = row_ptr[n + 1];
    int deg = end - beg;
    int myc = col[beg + min(lane, deg - 1)];
    float m = -3.0e38f, l = 0.f;
    float4 acc = make_float4(0.f, 0.f, 0.f, 0.f);
    auto loadx = [&](int i) -> ushort4 {
        if (i < deg) {
            int s = (i < 64) ? __shfl(myc, i) : col[beg + i];
            return *(const ushort4*)&xl[(size_t)s * D + c4];
        }
        return make_ushort4(0, 0, 0, 0);
    };
    auto step = [&](ushort4 x4) {
        float4 xlv = make_float4(bf2f(x4.x), bf2f(x4.y), bf2f(x4.z), bf2f(x4.w));
        float sx = xlv.x + xrv.x; sx = sx > 0.f ? sx : NEG * sx;
        float sy = xlv.y + xrv.y; sy = sy > 0.f ? sy : NEG * sy;
        float sz = xlv.z + xrv.z; sz = sz > 0.f ? sz : NEG * sz;
        float sw = xlv.w + xrv.w; sw = sw > 0.f ? sw : NEG * sw;
        float z = av.x * sx + av.y * sy + av.z * sz + av.w * sw;
        z += __shfl_xor(z, 1); z += __shfl_xor(z, 2); z += __shfl_xor(z, 4);
        float mn = fmaxf(m, z);
        float sc = __expf(m - mn);
        float p  = __expf(z - mn);
        l = l * sc + p;
        acc.x = acc.x * sc + p * xlv.x;
        acc.y = acc.y * sc + p * xlv.y;
        acc.z = acc.z * sc + p * xlv.z;
        acc.w = acc.w * sc + p * xlv.w;
        m = mn;
    };
    ushort4 b0 = loadx(0), b1 = loadx(1), b2 = loadx(2), b3 = loadx(3);
    int e = 0;
    for (; e + 4 <= deg; e += 4) {
        ushort4 n0 = loadx(e + 4), n1 = loadx(e + 5), n2 = loadx(e + 6), n3 = loadx(e + 7);
        step(b0); step(b1); step(b2); step(b3);
        b0 = n0; b1 = n1; b2 = n2; b3 = n3;
    }
    if (e + 0 < deg) step(b0);
    if (e + 1 < deg) step(b1);
    if (e + 2 < deg) step(b2);
    float4 gbv = *(const float4*)&gb[c4];
    float rl = 1.f / l;
    float4 o = make_float4(acc.x * rl + gbv.x, acc.y * rl + gbv.y,
                           acc.z * rl + gbv.z, acc.w * rl + gbv.w);
    float s = o.x + o.y + o.z + o.w;
#pragma unroll
    for (int msk = 1; msk <= 32; msk <<= 1) s += __shfl_xor(s, msk);
    float mu = s * (1.f / D);
    float4 dv = make_float4(o.x - mu, o.y - mu, o.z - mu, o.w - mu);
    float v2 = dv.x * dv.x + dv.y * dv.y + dv.z * dv.z + dv.w * dv.w;
#pragma unroll
    for (int msk = 1; msk <= 32; msk <<= 1) v2 += __shfl_xor(v2, msk);
    float rstd = rsqrtf(v2 * (1.f / D) + 1e-5f);
    float4 glsv = *(const float4*)&gls[c4];
    float4 glbv = *(const float4*)&glb[c4];
    float y0 = dv.x * rstd * glsv.x + glbv.x;
    float y1 = dv.y * rstd * glsv.y + glbv.y;
    float y2 = dv.z * rstd * glsv.z + glbv.z;
    float y3 = dv.w * rstd * glsv.w + glbv.w;
    y0 = y0 > 0.f ? y0 : expm1f(y0);
    y1 = y1 > 0.f ? y1 : expm1f(y1);
    y2 = y2 > 0.f ? y2 : expm1f(y2);
    y3 = y3 > 0.f ? y3 : expm1f(y3);
    float4 prev = make_float4(0.f, 0.f, 0.f, 0.f);
    if (layer > 0) prev = *(const float4*)&h[(size_t)n * D + c4];
    *(float4*)&h[(size_t)n * D + c4] =
        make_float4(prev.x + y0, prev.y + y1, prev.z + y2, prev.w + y3);
}

__device__ inline void color_tile(const float* h, const unsigned short* W1p, const float* b1,
                                  const unsigned short* W2p, const float* b2,
                                  const unsigned short* W3p, const float* b3,
                                  float* out, int N, int tt, int T,
                                  unsigned short (*As)[264], unsigned short (*Zs)[264]) {
    int lane = T & 63, w = T >> 6;
    int nb = tt * 16;
#pragma unroll
    for (int r = 0; r < 16; r++) {
        int row = nb + r;
        float v = (row < N) ? h[(size_t)row * D + T] : 0.f;
        As[r][T] = f2bf(v);
    }
    __syncthreads();
    int m = lane & 15;
    int q = lane >> 4;
    {
        f32x4 acc[4];
#pragma unroll
        for (int ct = 0; ct < 4; ct++) {
            float bv = b1[(w * 4 + ct) * 16 + m];
            acc[ct] = (f32x4){bv, bv, bv, bv};
        }
#pragma unroll 2
        for (int ks = 0; ks < 8; ks++) {
            bfrag af = *(const bfrag*)&As[m][ks * 32 + q * 8];
#pragma unroll
            for (int ct = 0; ct < 4; ct++) {
                int ctg = w * 4 + ct;
                bfrag bf = *(const bfrag*)&W1p[(((size_t)ctg * 8 + ks) * 64 + lane) * 8];
                acc[ct] = __builtin_amdgcn_mfma_f32_16x16x32_bf16(af, bf, acc[ct], 0, 0, 0);
            }
        }
#pragma unroll
        for (int ct = 0; ct < 4; ct++) {
            int colg = (w * 4 + ct) * 16 + m;
#pragma unroll
            for (int reg = 0; reg < 4; reg++)
                Zs[q * 4 + reg][colg] = f2bf(fmaxf(acc[ct][reg], 0.f));
        }
    }
    __syncthreads();
    {
        f32x4 acc[2];
#pragma unroll
        for (int ct = 0; ct < 2; ct++) {
            float bv = b2[(w * 2 + ct) * 16 + m];
            acc[ct] = (f32x4){bv, bv, bv, bv};
        }
#pragma unroll 2
        for (int ks = 0; ks < 8; ks++) {
            bfrag af = *(const bfrag*)&Zs[m][ks * 32 + q * 8];
#pragma unroll
            for (int ct = 0; ct < 2; ct++) {
                int ctg = w * 2 + ct;
                bfrag bf = *(const bfrag*)&W2p[(((size_t)ctg * 8 + ks) * 64 + lane) * 8];
                acc[ct] = __builtin_amdgcn_mfma_f32_16x16x32_bf16(af, bf, acc[ct], 0, 0, 0);
            }
        }
        __syncthreads();
#pragma unroll
        for (int ct = 0; ct < 2; ct++) {
            int colg = (w * 2 + ct) * 16 + m;
#pragma unroll
            for (int reg = 0; reg < 4; reg++)
                As[q * 4 + reg][colg] = f2bf(fmaxf(acc[ct][reg], 0.f));
        }
    }
    __syncthreads();
    for (int ctg = w; ctg < 13; ctg += 4) {
        int colg = ctg * 16 + m;
        float bv = (colg < MC) ? b3[colg] : 0.f;
        f32x4 acc = (f32x4){bv, bv, bv, bv};
#pragma unroll
        for (int ks = 0; ks < 4; ks++) {
            bfrag af = *(const bfrag*)&As[m][ks * 32 + q * 8];
            bfrag bf = *(const bfrag*)&W3p[(((size_t)ctg * 4 + ks) * 64 + lane) * 8];
            acc = __builtin_amdgcn_mfma_f32_16x16x32_bf16(af, bf, acc, 0, 0, 0);
        }
#pragma unroll
        for (int reg = 0; reg < 4; reg++) {
            int row = nb + q * 4 + reg;
            if (row < N && colg < MC) out[(size_t)row * MC + colg] = acc[reg];
        }
    }
}

// ---------------------------------------------------------------- the persistent mega kernel
__global__ __launch_bounds__(256, 2) void mega_k(MegaArgs A) {
    __shared__ ShMem sh;
    const int B = blockIdx.x, T = threadIdx.x, NBK = gridDim.x;
    const int gid = B * 256 + T, gstr = NBK * 256;
    const int lane = T & 63, wv = T >> 6;
    unsigned gen = 0;

    auto BAR = [&]() {
        __syncthreads();
        gen += (unsigned)NBK;
        if (T == 0) {
            __threadfence();
            __hip_atomic_fetch_add(A.bar, 1u, __ATOMIC_RELEASE, __HIP_MEMORY_SCOPE_AGENT);
            while (__hip_atomic_load(A.bar, __ATOMIC_ACQUIRE, __HIP_MEMORY_SCOPE_AGENT) < gen)
                __builtin_amdgcn_s_sleep(1);
            __threadfence();
        }
        __syncthreads();
    };

    // ---- P0: deg init + weight repacks + encoder (all independent)
    for (int i = gid; i < A.N; i += gstr) A.deg[i] = 1;
    for (int tid = gid; tid < NL * 2 * 16 * 8 * 64; tid += gstr) repack_attn_one(A.Wl, A.Wr, A.Wp, tid);
    for (int tid = gid; tid < 16 * 8 * 64; tid += gstr) repack_gen_one(A.cW1, A.cW1p, D, D, 8, tid);
    for (int tid = gid; tid < 8 * 8 * 64; tid += gstr)  repack_gen_one(A.cW2, A.cW2p, D, 128, 8, tid);
    for (int tid = gid; tid < 13 * 4 * 64; tid += gstr) repack_gen_one(A.cW3, A.cW3p, 128, MC, 4, tid);
    for (int n = B * 4 + wv; n < A.N; n += NBK * 4)
        enc_node(A.x, A.encW, A.encb, A.encls, A.enclb, A.h, n, lane);
    BAR();

    // ---- P1: degree count
    for (int e = gid; e < A.E; e += gstr) atomicAdd(&A.deg[A.edst[e]], 1);
    BAR();

    // ---- P2: per-block chunk sums
    const int chunk = (A.N + NBK - 1) / NBK;
    const int lo = B * chunk, hi = min(lo + chunk, A.N);
    if (T == 0) {
        int s = 0;
        for (int i = lo; i < hi; i++) s += A.deg[i];
        A.part[B] = s;
    }
    BAR();

    // ---- P3: block 0 scans the NBK partials (pairs: 512 entries, 256 threads)
    if (B == 0) {
        int a0 = A.part[2 * T], a1 = A.part[2 * T + 1];
        int s = a0 + a1;
        sh.scan[T] = s;
        __syncthreads();
        for (int off = 1; off < 256; off <<= 1) {
            int v = (T >= off) ? sh.scan[T - off] : 0;
            __syncthreads();
            sh.scan[T] += v;
            __syncthreads();
        }
        int incl = sh.scan[T];
        int excl = incl - s;
        A.part2[2 * T] = excl;
        A.part2[2 * T + 1] = excl + a0;
        if (T == 255) A.row_ptr[A.N] = incl;
    }
    BAR();

    // ---- P4: row_ptr / fill within chunk
    if (T == 0) {
        int run = A.part2[B];
        for (int i = lo; i < hi; i++) {
            A.row_ptr[i] = run; A.fill[i] = run;
            run += A.deg[i];
        }
    }
    BAR();

    // ---- P5: scatter (edges + self loops)
    for (int e = gid; e < A.E + A.N; e += gstr) {
        if (e < A.E) {
            int p = atomicAdd(&A.fill[A.edst[e]], 1);
            A.col[p] = A.esrc[e];
        } else {
            int n = e - A.E;
            int p = atomicAdd(&A.fill[n], 1);
            A.col[p] = n;
        }
    }
    BAR();

    // ---- 6 GATv2 layers: gemm phase | barrier | attn phase | barrier
    const int ntiles = (A.N + 15) >> 4;
    for (int l = 0; l < NL; l++) {
        const unsigned short* WpL = A.Wp + (size_t)(l * 2 + 0) * 65536;
        const unsigned short* WpR = A.Wp + (size_t)(l * 2 + 1) * 65536;
        for (int tt = B; tt < ntiles; tt += NBK) {
            gemm_tile(A.h, WpL, WpR, A.bl + l * D, A.br + l * D, A.xl, A.xr, A.N, tt, T, sh.mm.As);
            __syncthreads();
        }
        BAR();
        for (int n0 = B * 4; n0 < A.N; n0 += NBK * 4) {
            int n = n0 + wv;
            if (n < A.N)
                attn_node(A.xl, A.xr, A.row_ptr, A.col, A.att + l * NH * NC,
                          A.gb + l * D, A.gls + l * D, A.glb + l * D, A.h, l, n, lane);
        }
        BAR();
    }

    // ---- color head (MFMA) + pooling, same phase (both read-only on h)
    for (int tt = B; tt < ntiles; tt += NBK) {
        color_tile(A.h, A.cW1p, A.cb1, A.cW2p, A.cb2, A.cW3p, A.cb3, A.out_colors, A.N, tt, T,
                   sh.mm.As, sh.mm.Zs);
        __syncthreads();
    }
    for (int task = B; task < BG * PS; task += NBK) {
        int b = task / PS, sl = task % PS;
        int l2 = 0, h2 = A.N;
        while (l2 < h2) { int mid = (l2 + h2) >> 1; if (A.batch[mid] < b) l2 = mid + 1; else h2 = mid; }
        int s0 = l2;
        l2 = 0; h2 = A.N;
        while (l2 < h2) { int mid = (l2 + h2) >> 1; if (A.batch[mid] < b + 1) l2 = mid + 1; else h2 = mid; }
        int s1 = l2;
        int len = s1 - s0;
        int ch = (len + PS - 1) / PS;
        int n0 = s0 + sl * ch;
        int n1 = min(n0 + ch, s1);
        float sum = 0.f, mx = -3.0e38f;
        for (int n = n0; n < n1; n++) {
            float v = A.h[(size_t)n * D + T];
            sum += v;
            mx = fmaxf(mx, v);
        }
        A.psum[(size_t)(b * PS + sl) * D + T] = sum;
        A.pmax[(size_t)(b * PS + sl) * D + T] = mx;
        if (T == 0 && sl == 0) A.cnt[b] = len;
    }
    BAR();

    // ---- graph heads (48 tasks)
    for (int task = B; task < BG * 3; task += NBK) {
        int b = task / 3, sec = task % 3;
        float sum = 0.f, mx = -3.0e38f;
#pragma unroll
        for (int sl = 0; sl < PS; sl++) {
            sum += A.psum[(size_t)(b * PS + sl) * D + T];
            mx = fmaxf(mx, A.pmax[(size_t)(b * PS + sl) * D + T]);
        }
        int cn = A.cnt[b];
        float c = fmaxf((float)cn, 1.f);
        sh.hd.g[T] = sum / c;
        sh.hd.g[D + T] = (cn > 0) ? mx : 0.f;
        __syncthreads();
        if (sec == 0) {
            sh.hd.z1[T] = fmaxf(A.chb1[T] + dot_ilp(sh.hd.g, A.chW1, 2 * D, D, T), 0.f);
            __syncthreads();
            if (T < 128) sh.hd.z2[T] = fmaxf(A.chb2[T] + dot_ilp(sh.hd.z1, A.chW2, D, 128, T), 0.f);
            __syncthreads();
            if (T < MC) A.out_ch[b * MC + T] = A.chb3[T] + dot_ilp(sh.hd.z2, A.chW3, 128, MC, T);
        } else if (sec == 1) {
            if (T < 128) sh.hd.z1[T] = fmaxf(A.tb1[T] + dot_ilp(sh.hd.g, A.tW1, 2 * D, 128, T), 0.f);
            __syncthreads();
            if (T < NT) A.out_t[b * NT + T] = A.tb2[T] + dot_ilp(sh.hd.z1, A.tW2, 128, NT, T);
        } else {
            if (T < 64) sh.hd.z1[T] = fmaxf(A.db1[T] + dot_ilp(sh.hd.g, A.dW1, 2 * D, 64, T), 0.f);
            __syncthreads();
            if (T == 0) {
                float a = A.db2[0] + dot_ilp(sh.hd.z1, A.dW2, 64, 1, 0);
                A.out_d[b] = 100.f / (1.f + __expf(-a));
            }
        }
        __syncthreads();
    }
}

// ----------------------------------------------------------------
extern "C" void kernel_launch(void* const* d_in, const int* in_sizes, int n_in,
                              void* d_out, int out_size, void* d_ws, size_t ws_size,
                              hipStream_t stream) {
    MegaArgs A;
    A.x     = (const float*)d_in[0];
    const int* ei = (const int*)d_in[1];
    A.batch = (const int*)d_in[2];
    A.encW  = (const float*)d_in[3];
    A.encb  = (const float*)d_in[4];
    A.encls = (const float*)d_in[5];
    A.enclb = (const float*)d_in[6];
    A.Wl    = (const float*)d_in[7];
    A.bl    = (const float*)d_in[8];
    A.Wr    = (const float*)d_in[9];
    A.br    = (const float*)d_in[10];
    A.att   = (const float*)d_in[11];
    A.gb    = (const float*)d_in[12];
    A.gls   = (const float*)d_in[13];
    A.glb   = (const float*)d_in[14];
    A.cW1   = (const float*)d_in[15];
    A.cb1   = (const float*)d_in[16];
    A.cW2   = (const float*)d_in[17];
    A.cb2   = (const float*)d_in[18];
    A.cW3   = (const float*)d_in[19];
    A.cb3   = (const float*)d_in[20];
    A.chW1  = (const float*)d_in[21];
    A.chb1  = (const float*)d_in[22];
    A.chW2  = (const float*)d_in[23];
    A.chb2  = (const float*)d_in[24];
    A.chW3  = (const float*)d_in[25];
    A.chb3  = (const float*)d_in[26];
    A.tW1   = (const float*)d_in[27];
    A.tb1   = (const float*)d_in[28];
    A.tW2   = (const float*)d_in[29];
    A.tb2   = (const float*)d_in[30];
    A.dW1   = (const float*)d_in[31];
    A.db1   = (const float*)d_in[32];
    A.dW2   = (const float*)d_in[33];
    A.db2   = (const float*)d_in[34];

    A.N = in_sizes[0] / DIN;
    A.E = in_sizes[1] / 2;
    A.esrc = ei;
    A.edst = ei + A.E;

    char* p = (char*)d_ws;
    auto carve = [&](size_t bytes) { char* r = p; p += (bytes + 255) & ~(size_t)255; return r; };
    A.bar     = (unsigned*)carve(256);
    A.row_ptr = (int*)carve((size_t)(A.N + 1) * 4);
    A.fill    = (int*)carve((size_t)A.N * 4);
    A.deg     = (int*)carve((size_t)A.N * 4);
    A.cnt     = (int*)carve((size_t)BG * 4);
    A.part    = (int*)carve((size_t)NB * 4);
    A.part2   = (int*)carve((size_t)NB * 4);
    A.psum    = (float*)carve((size_t)BG * PS * D * 4);
    A.pmax    = (float*)carve((size_t)BG * PS * D * 4);
    A.col     = (int*)carve((size_t)(A.E + A.N) * 4);
    A.Wp      = (unsigned short*)carve((size_t)NL * 2 * 65536 * 2);
    A.cW1p    = (unsigned short*)carve((size_t)16 * 8 * 64 * 8 * 2);
    A.cW2p    = (unsigned short*)carve((size_t)8 * 8 * 64 * 8 * 2);
    A.cW3p    = (unsigned short*)carve((size_t)13 * 4 * 64 * 8 * 2);
    A.h       = (float*)carve((size_t)A.N * D * 4);
    A.xl      = (unsigned short*)carve((size_t)A.N * D * 2);
    A.xr      = (unsigned short*)carve((size_t)A.N * D * 2);
    (void)ws_size; (void)n_in; (void)out_size;

    float* out = (float*)d_out;
    A.out_colors = out;
    A.out_ch = out + (size_t)A.N * MC;
    A.out_t  = out + (size_t)A.N * MC + BG * MC;
    A.out_d  = out + (size_t)A.N * MC + BG * MC + BG * NT;

    hipMemsetAsync(A.bar, 0, 4, stream);
    mega_k<<<NB, 256, 0, stream>>>(A);
}

// Round 11
// 528.668 us; speedup vs baseline: 4.3098x; 4.3098x over previous
//
#include <hip/hip_runtime.h>
#include <hip/hip_bf16.h>

constexpr int DIN = 16;
constexpr int D   = 256;
constexpr int NH  = 8;
constexpr int NC  = 32;
constexpr int MC  = 200;
constexpr int NT  = 8;
constexpr int BG  = 16;
constexpr int NL  = 6;
constexpr int PS  = 16;   // pool slices per graph
constexpr float NEG = 0.2f;

typedef __attribute__((ext_vector_type(8))) short bfrag;
typedef __attribute__((ext_vector_type(4))) float f32x4;

__device__ inline unsigned short f2bf(float f) {
    unsigned int u = __float_as_uint(f);
    u += 0x7FFFu + ((u >> 16) & 1u);
    return (unsigned short)(u >> 16);
}
__device__ inline float bf2f(unsigned short u) {
    return __uint_as_float((unsigned int)u << 16);
}

__device__ inline float dot_ilp(const float* g, const float* __restrict__ W, int K, int ldw, int t) {
    float a0 = 0.f, a1 = 0.f, a2 = 0.f, a3 = 0.f;
    for (int k = 0; k < K; k += 4) {
        a0 = fmaf(g[k + 0], W[(k + 0) * ldw + t], a0);
        a1 = fmaf(g[k + 1], W[(k + 1) * ldw + t], a1);
        a2 = fmaf(g[k + 2], W[(k + 2) * ldw + t], a2);
        a3 = fmaf(g[k + 3], W[(k + 3) * ldw + t], a3);
    }
    return (a0 + a1) + (a2 + a3);
}

// ---------------- device helpers ----------------

__device__ inline void enc_node(const float* x, const float* W, const float* b, const float* ls,
                                const float* lb, float* h, int n, int lane) {
    int c4 = lane * 4;
    float xs[DIN];
#pragma unroll
    for (int k = 0; k < DIN; k += 4) {
        float4 xv = *(const float4*)&x[n * DIN + k];
        xs[k] = xv.x; xs[k + 1] = xv.y; xs[k + 2] = xv.z; xs[k + 3] = xv.w;
    }
    float4 a = *(const float4*)&b[c4];
#pragma unroll
    for (int k = 0; k < DIN; k++) {
        float4 wv = *(const float4*)&W[k * D + c4];
        a.x = fmaf(xs[k], wv.x, a.x);
        a.y = fmaf(xs[k], wv.y, a.y);
        a.z = fmaf(xs[k], wv.z, a.z);
        a.w = fmaf(xs[k], wv.w, a.w);
    }
    float s = a.x + a.y + a.z + a.w;
#pragma unroll
    for (int msk = 1; msk <= 32; msk <<= 1) s += __shfl_xor(s, msk);
    float mu = s * (1.f / D);
    float4 dv = make_float4(a.x - mu, a.y - mu, a.z - mu, a.w - mu);
    float v2 = dv.x * dv.x + dv.y * dv.y + dv.z * dv.z + dv.w * dv.w;
#pragma unroll
    for (int msk = 1; msk <= 32; msk <<= 1) v2 += __shfl_xor(v2, msk);
    float rstd = rsqrtf(v2 * (1.f / D) + 1e-5f);
    float4 lsv = *(const float4*)&ls[c4];
    float4 lbv = *(const float4*)&lb[c4];
    float4 y = make_float4(fmaxf(dv.x * rstd * lsv.x + lbv.x, 0.f),
                           fmaxf(dv.y * rstd * lsv.y + lbv.y, 0.f),
                           fmaxf(dv.z * rstd * lsv.z + lbv.z, 0.f),
                           fmaxf(dv.w * rstd * lsv.w + lbv.w, 0.f));
    *(float4*)&h[(size_t)n * D + c4] = y;
}

// attn for one node; returns residual-added output (4 channels of this lane)
__device__ inline float4 attn_compute(const unsigned short* xl, const unsigned short* xr,
                                      const int* row_ptr, const int* col, const float* att,
                                      const float* gb, const float* gls, const float* glb,
                                      const float* h, int layer, int n, int lane) {
    int c4 = lane * 4;
    ushort4 xr4 = *(const ushort4*)&xr[(size_t)n * D + c4];
    float4 xrv = make_float4(bf2f(xr4.x), bf2f(xr4.y), bf2f(xr4.z), bf2f(xr4.w));
    float4 av  = *(const float4*)&att[c4];
    int beg = row_ptr[n], end = row_ptr[n + 1];
    int deg = end - beg;
    int myc = col[beg + min(lane, deg - 1)];
    float m = -3.0e38f, l = 0.f;
    float4 acc = make_float4(0.f, 0.f, 0.f, 0.f);
    auto loadx = [&](int i) -> ushort4 {
        if (i < deg) {
            int s = (i < 64) ? __shfl(myc, i) : col[beg + i];
            return *(const ushort4*)&xl[(size_t)s * D + c4];
        }
        return make_ushort4(0, 0, 0, 0);
    };
    auto step = [&](ushort4 x4) {
        float4 xlv = make_float4(bf2f(x4.x), bf2f(x4.y), bf2f(x4.z), bf2f(x4.w));
        float sx = xlv.x + xrv.x; sx = sx > 0.f ? sx : NEG * sx;
        float sy = xlv.y + xrv.y; sy = sy > 0.f ? sy : NEG * sy;
        float sz = xlv.z + xrv.z; sz = sz > 0.f ? sz : NEG * sz;
        float sw = xlv.w + xrv.w; sw = sw > 0.f ? sw : NEG * sw;
        float z = av.x * sx + av.y * sy + av.z * sz + av.w * sw;
        z += __shfl_xor(z, 1); z += __shfl_xor(z, 2); z += __shfl_xor(z, 4);
        float mn = fmaxf(m, z);
        float sc = __expf(m - mn);
        float p  = __expf(z - mn);
        l = l * sc + p;
        acc.x = acc.x * sc + p * xlv.x;
        acc.y = acc.y * sc + p * xlv.y;
        acc.z = acc.z * sc + p * xlv.z;
        acc.w = acc.w * sc + p * xlv.w;
        m = mn;
    };
    ushort4 b0 = loadx(0), b1 = loadx(1), b2 = loadx(2), b3 = loadx(3);
    int e = 0;
    for (; e + 4 <= deg; e += 4) {
        ushort4 n0 = loadx(e + 4), n1 = loadx(e + 5), n2 = loadx(e + 6), n3 = loadx(e + 7);
        step(b0); step(b1); step(b2); step(b3);
        b0 = n0; b1 = n1; b2 = n2; b3 = n3;
    }
    if (e + 0 < deg) step(b0);
    if (e + 1 < deg) step(b1);
    if (e + 2 < deg) step(b2);
    float4 gbv = *(const float4*)&gb[c4];
    float rl = 1.f / l;
    float4 o = make_float4(acc.x * rl + gbv.x, acc.y * rl + gbv.y,
                           acc.z * rl + gbv.z, acc.w * rl + gbv.w);
    float s = o.x + o.y + o.z + o.w;
#pragma unroll
    for (int msk = 1; msk <= 32; msk <<= 1) s += __shfl_xor(s, msk);
    float mu = s * (1.f / D);
    float4 dv = make_float4(o.x - mu, o.y - mu, o.z - mu, o.w - mu);
    float v2 = dv.x * dv.x + dv.y * dv.y + dv.z * dv.z + dv.w * dv.w;
#pragma unroll
    for (int msk = 1; msk <= 32; msk <<= 1) v2 += __shfl_xor(v2, msk);
    float rstd = rsqrtf(v2 * (1.f / D) + 1e-5f);
    float4 glsv = *(const float4*)&gls[c4];
    float4 glbv = *(const float4*)&glb[c4];
    float y0 = dv.x * rstd * glsv.x + glbv.x;
    float y1 = dv.y * rstd * glsv.y + glbv.y;
    float y2 = dv.z * rstd * glsv.z + glbv.z;
    float y3 = dv.w * rstd * glsv.w + glbv.w;
    y0 = y0 > 0.f ? y0 : expm1f(y0);
    y1 = y1 > 0.f ? y1 : expm1f(y1);
    y2 = y2 > 0.f ? y2 : expm1f(y2);
    y3 = y3 > 0.f ? y3 : expm1f(y3);
    float4 prev = make_float4(0.f, 0.f, 0.f, 0.f);
    if (layer > 0) prev = *(const float4*)&h[(size_t)n * D + c4];
    return make_float4(prev.x + y0, prev.y + y1, prev.z + y2, prev.w + y3);
}

// MFMA tile GEMM reading A-fragments from As (already bf16), writing xl/xr bf16
__device__ inline void gemm_core(const unsigned short (*As)[264],
                                 const unsigned short* WpL, const unsigned short* WpR,
                                 const float* bl, const float* br,
                                 unsigned short* xl, unsigned short* xr, int N, int nb, int T) {
    int lane = T & 63, w = T >> 6;
    int m = lane & 15, q = lane >> 4;
    int ctbase = w * 4;
    f32x4 accL[4], accR[4];
#pragma unroll
    for (int ct = 0; ct < 4; ct++) {
        float bLv = bl[(ctbase + ct) * 16 + m];
        float bRv = br[(ctbase + ct) * 16 + m];
        accL[ct] = (f32x4){bLv, bLv, bLv, bLv};
        accR[ct] = (f32x4){bRv, bRv, bRv, bRv};
    }
#pragma unroll 2
    for (int ks = 0; ks < 8; ks++) {
        bfrag af = *(const bfrag*)&As[m][ks * 32 + q * 8];
#pragma unroll
        for (int ct = 0; ct < 4; ct++) {
            int ctg = ctbase + ct;
            size_t off = (((size_t)ctg * 8 + ks) * 64 + lane) * 8;
            bfrag bL = *(const bfrag*)&WpL[off];
            bfrag bR = *(const bfrag*)&WpR[off];
            accL[ct] = __builtin_amdgcn_mfma_f32_16x16x32_bf16(af, bL, accL[ct], 0, 0, 0);
            accR[ct] = __builtin_amdgcn_mfma_f32_16x16x32_bf16(af, bR, accR[ct], 0, 0, 0);
        }
    }
#pragma unroll
    for (int ct = 0; ct < 4; ct++) {
        int colg = (ctbase + ct) * 16 + m;
#pragma unroll
        for (int reg = 0; reg < 4; reg++) {
            int row = nb + q * 4 + reg;
            if (row < N) {
                xl[(size_t)row * D + colg] = f2bf(accL[ct][reg]);
                xr[(size_t)row * D + colg] = f2bf(accR[ct][reg]);
            }
        }
    }
}

__device__ inline void repack_attn_one(const float* Wl, const float* Wr, unsigned short* Wp, int tid) {
    int lane = tid & 63;
    int r1 = tid >> 6;
    int ks = r1 & 7;
    int r2 = r1 >> 3;
    int ct = r2 & 15;
    int mi = r2 >> 4;
    int layer = mi >> 1, mat = mi & 1;
    const float* W = (mat == 0 ? Wl : Wr) + (size_t)layer * D * D;
    int n = ct * 16 + (lane & 15);
    int kb = ks * 32 + (lane >> 4) * 8;
    size_t base = (((size_t)(mi * 16 + ct) * 8 + ks) * 64 + lane) * 8;
#pragma unroll
    for (int j = 0; j < 8; j++) Wp[base + j] = f2bf(W[(size_t)(kb + j) * D + n]);
}

__device__ inline void repack_gen_one(const float* W, unsigned short* Wp, int K, int NCOL, int nks, int tid) {
    int lane = tid & 63;
    int r = tid >> 6;
    int ks = r % nks;
    int ct = r / nks;
    int n = ct * 16 + (lane & 15);
    int kb = ks * 32 + (lane >> 4) * 8;
    size_t base = (((size_t)ct * nks + ks) * 64 + lane) * 8;
#pragma unroll
    for (int j = 0; j < 8; j++) {
        int k = kb + j;
        Wp[base + j] = (n < NCOL && k < K) ? f2bf(W[(size_t)k * NCOL + n]) : (unsigned short)0;
    }
}

// ---------------- kernels (12 dispatches total) ----------------

// d1: deg=1 + encoder (wave per node)
__global__ __launch_bounds__(256) void init_enc_k(const float* __restrict__ x, const float* __restrict__ W,
                                                  const float* __restrict__ b, const float* __restrict__ ls,
                                                  const float* __restrict__ lb, float* __restrict__ h,
                                                  int* __restrict__ deg, int N) {
    int gid = blockIdx.x * 256 + threadIdx.x;
    if (gid < N) deg[gid] = 1;
    int lane = threadIdx.x & 63;
    int n = blockIdx.x * 4 + (threadIdx.x >> 6);
    if (n < N) enc_node(x, W, b, ls, lb, h, n, lane);
}

// d2: edge count + all weight repacks
__global__ __launch_bounds__(256) void count_repack_k(const int* __restrict__ dst, int* __restrict__ deg, int E,
                                                      const float* __restrict__ Wl, const float* __restrict__ Wr,
                                                      unsigned short* __restrict__ Wp,
                                                      const float* __restrict__ cW1, unsigned short* __restrict__ cW1p,
                                                      const float* __restrict__ cW2, unsigned short* __restrict__ cW2p,
                                                      const float* __restrict__ cW3, unsigned short* __restrict__ cW3p) {
    int gid = blockIdx.x * 256 + threadIdx.x;
    if (gid < E) atomicAdd(&deg[dst[gid]], 1);
    if (gid < NL * 2 * 16 * 8 * 64) repack_attn_one(Wl, Wr, Wp, gid);
    if (gid < 16 * 8 * 64) repack_gen_one(cW1, cW1p, D, D, 8, gid);
    if (gid < 8 * 8 * 64)  repack_gen_one(cW2, cW2p, D, 128, 8, gid);
    if (gid < 13 * 4 * 64) repack_gen_one(cW3, cW3p, 128, MC, 4, gid);
}

// d3: single-block scan
__global__ __launch_bounds__(1024) void scan_k(const int* __restrict__ deg, int* __restrict__ row_ptr,
                                               int* __restrict__ fill, int N) {
    __shared__ int sd[1024];
    int t = threadIdx.x;
    int chunk = (N + 1023) >> 10;
    int lo = t * chunk, hi = min(lo + chunk, N);
    int s = 0;
    for (int i = lo; i < hi; i++) s += deg[i];
    sd[t] = s;
    __syncthreads();
    for (int off = 1; off < 1024; off <<= 1) {
        int v = (t >= off) ? sd[t - off] : 0;
        __syncthreads();
        sd[t] += v;
        __syncthreads();
    }
    int run = (t > 0) ? sd[t - 1] : 0;
    for (int i = lo; i < hi; i++) {
        row_ptr[i] = run; fill[i] = run;
        run += deg[i];
    }
    if (t == 1023) row_ptr[N] = sd[1023];
}

// d4: scatter + layer-0 GEMM (independent jobs, one dispatch)
__global__ __launch_bounds__(256) void scatter_gemm0_k(const int* __restrict__ src, const int* __restrict__ dst,
                                                       int* __restrict__ fill, int* __restrict__ col, int E, int N,
                                                       const float* __restrict__ h,
                                                       const unsigned short* __restrict__ WpL,
                                                       const unsigned short* __restrict__ WpR,
                                                       const float* __restrict__ bl, const float* __restrict__ br,
                                                       unsigned short* __restrict__ xl, unsigned short* __restrict__ xr) {
    __shared__ unsigned short As[16][264];
    int T = threadIdx.x;
    int tt = blockIdx.x;
    int ntiles = (N + 15) >> 4;
    if (tt < ntiles) {
        int nb = tt * 16;
#pragma unroll
        for (int r = 0; r < 16; r++) {
            int row = nb + r;
            float v = (row < N) ? h[(size_t)row * D + T] : 0.f;
            As[r][T] = f2bf(v);
        }
        __syncthreads();
        gemm_core(As, WpL, WpR, bl, br, xl, xr, N, nb, T);
    }
    for (int e = blockIdx.x * 256 + T; e < E + N; e += gridDim.x * 256) {
        if (e < E) {
            int p = atomicAdd(&fill[dst[e]], 1);
            col[p] = src[e];
        } else {
            int n = e - E;
            int p = atomicAdd(&fill[n], 1);
            col[p] = n;
        }
    }
}

// d5..d9: fused attn(layer l, reads xl_in/xr_in) + gemm(layer l+1, writes xl_out/xr_out)
__global__ __launch_bounds__(256) void layer_k(const unsigned short* __restrict__ xl_in,
                                               const unsigned short* __restrict__ xr_in,
                                               const int* __restrict__ row_ptr, const int* __restrict__ col,
                                               const float* __restrict__ att, const float* __restrict__ gb,
                                               const float* __restrict__ gls, const float* __restrict__ glb,
                                               float* __restrict__ h, int layer, int N,
                                               const unsigned short* __restrict__ WpL,
                                               const unsigned short* __restrict__ WpR,
                                               const float* __restrict__ bl, const float* __restrict__ br,
                                               unsigned short* __restrict__ xl_out, unsigned short* __restrict__ xr_out) {
    __shared__ unsigned short As[16][264];
    int T = threadIdx.x;
    int lane = T & 63, wv = T >> 6;
    int nb = blockIdx.x * 16;
    int c4 = lane * 4;
#pragma unroll
    for (int r0 = 0; r0 < 4; r0++) {
        int r = wv * 4 + r0;
        int n = nb + r;
        if (n < N) {
            float4 res = attn_compute(xl_in, xr_in, row_ptr, col, att, gb, gls, glb, h, layer, n, lane);
            *(float4*)&h[(size_t)n * D + c4] = res;
            As[r][c4 + 0] = f2bf(res.x);
            As[r][c4 + 1] = f2bf(res.y);
            As[r][c4 + 2] = f2bf(res.z);
            As[r][c4 + 3] = f2bf(res.w);
        } else {
            As[r][c4 + 0] = 0; As[r][c4 + 1] = 0; As[r][c4 + 2] = 0; As[r][c4 + 3] = 0;
        }
    }
    __syncthreads();
    gemm_core(As, WpL, WpR, bl, br, xl_out, xr_out, N, nb, T);
}

// d10: final attn (layer 5) + fused color-head MFMA MLP
__global__ __launch_bounds__(256) void last_k(const unsigned short* __restrict__ xl_in,
                                              const unsigned short* __restrict__ xr_in,
                                              const int* __restrict__ row_ptr, const int* __restrict__ col,
                                              const float* __restrict__ att, const float* __restrict__ gb,
                                              const float* __restrict__ gls, const float* __restrict__ glb,
                                              float* __restrict__ h, int N,
                                              const unsigned short* __restrict__ W1p, const float* __restrict__ b1,
                                              const unsigned short* __restrict__ W2p, const float* __restrict__ b2,
                                              const unsigned short* __restrict__ W3p, const float* __restrict__ b3,
                                              float* __restrict__ out) {
    __shared__ unsigned short As[16][264];
    __shared__ unsigned short Zs[16][264];
    int T = threadIdx.x;
    int lane = T & 63, wv = T >> 6;
    int nb = blockIdx.x * 16;
    int c4 = lane * 4;
#pragma unroll
    for (int r0 = 0; r0 < 4; r0++) {
        int r = wv * 4 + r0;
        int n = nb + r;
        if (n < N) {
            float4 res = attn_compute(xl_in, xr_in, row_ptr, col, att, gb, gls, glb, h, NL - 1, n, lane);
            *(float4*)&h[(size_t)n * D + c4] = res;
            As[r][c4 + 0] = f2bf(res.x);
            As[r][c4 + 1] = f2bf(res.y);
            As[r][c4 + 2] = f2bf(res.z);
            As[r][c4 + 3] = f2bf(res.w);
        } else {
            As[r][c4 + 0] = 0; As[r][c4 + 1] = 0; As[r][c4 + 2] = 0; As[r][c4 + 3] = 0;
        }
    }
    __syncthreads();
    int m = lane & 15, q = lane >> 4, w = wv;
    {
        f32x4 acc[4];
#pragma unroll
        for (int ct = 0; ct < 4; ct++) {
            float bv = b1[(w * 4 + ct) * 16 + m];
            acc[ct] = (f32x4){bv, bv, bv, bv};
        }
#pragma unroll 2
        for (int ks = 0; ks < 8; ks++) {
            bfrag af = *(const bfrag*)&As[m][ks * 32 + q * 8];
#pragma unroll
            for (int ct = 0; ct < 4; ct++) {
                int ctg = w * 4 + ct;
                bfrag bf = *(const bfrag*)&W1p[(((size_t)ctg * 8 + ks) * 64 + lane) * 8];
                acc[ct] = __builtin_amdgcn_mfma_f32_16x16x32_bf16(af, bf, acc[ct], 0, 0, 0);
            }
        }
#pragma unroll
        for (int ct = 0; ct < 4; ct++) {
            int colg = (w * 4 + ct) * 16 + m;
#pragma unroll
            for (int reg = 0; reg < 4; reg++)
                Zs[q * 4 + reg][colg] = f2bf(fmaxf(acc[ct][reg], 0.f));
        }
    }
    __syncthreads();
    {
        f32x4 acc[2];
#pragma unroll
        for (int ct = 0; ct < 2; ct++) {
            float bv = b2[(w * 2 + ct) * 16 + m];
            acc[ct] = (f32x4){bv, bv, bv, bv};
        }
#pragma unroll 2
        for (int ks = 0; ks < 8; ks++) {
            bfrag af = *(const bfrag*)&Zs[m][ks * 32 + q * 8];
#pragma unroll
            for (int ct = 0; ct < 2; ct++) {
                int ctg = w * 2 + ct;
                bfrag bf = *(const bfrag*)&W2p[(((size_t)ctg * 8 + ks) * 64 + lane) * 8];
                acc[ct] = __builtin_amdgcn_mfma_f32_16x16x32_bf16(af, bf, acc[ct], 0, 0, 0);
            }
        }
        __syncthreads();
#pragma unroll
        for (int ct = 0; ct < 2; ct++) {
            int colg = (w * 2 + ct) * 16 + m;
#pragma unroll
            for (int reg = 0; reg < 4; reg++)
                As[q * 4 + reg][colg] = f2bf(fmaxf(acc[ct][reg], 0.f));
        }
    }
    __syncthreads();
    for (int ctg = w; ctg < 13; ctg += 4) {
        int colg = ctg * 16 + m;
        float bv = (colg < MC) ? b3[colg] : 0.f;
        f32x4 acc = (f32x4){bv, bv, bv, bv};
#pragma unroll
        for (int ks = 0; ks < 4; ks++) {
            bfrag af = *(const bfrag*)&As[m][ks * 32 + q * 8];
            bfrag bf = *(const bfrag*)&W3p[(((size_t)ctg * 4 + ks) * 64 + lane) * 8];
            acc = __builtin_amdgcn_mfma_f32_16x16x32_bf16(af, bf, acc, 0, 0, 0);
        }
#pragma unroll
        for (int reg = 0; reg < 4; reg++) {
            int row = nb + q * 4 + reg;
            if (row < N && colg < MC) out[(size_t)row * MC + colg] = acc[reg];
        }
    }
}

// d11: pooling stage 1
__global__ __launch_bounds__(256) void pool_k(const float* __restrict__ h, const int* __restrict__ batch,
                                              float* __restrict__ psum, float* __restrict__ pmax,
                                              int* __restrict__ cnt, int N) {
    int b = blockIdx.x;
    int sl = blockIdx.y;
    int c = threadIdx.x;
    int lo = 0, hi = N;
    while (lo < hi) { int mid = (lo + hi) >> 1; if (batch[mid] < b) lo = mid + 1; else hi = mid; }
    int s0 = lo;
    lo = 0; hi = N;
    while (lo < hi) { int mid = (lo + hi) >> 1; if (batch[mid] < b + 1) lo = mid + 1; else hi = mid; }
    int s1 = lo;
    int len = s1 - s0;
    int chunk = (len + PS - 1) / PS;
    int n0 = s0 + sl * chunk;
    int n1 = min(n0 + chunk, s1);
    float sum = 0.f, mx = -3.0e38f;
    for (int n = n0; n < n1; n++) {
        float v = h[(size_t)n * D + c];
        sum += v;
        mx = fmaxf(mx, v);
    }
    psum[(size_t)(b * PS + sl) * D + c] = sum;
    pmax[(size_t)(b * PS + sl) * D + c] = mx;
    if (c == 0 && sl == 0) cnt[b] = len;
}

// d12: graph heads
__global__ __launch_bounds__(256) void heads_k(const float* __restrict__ psum, const float* __restrict__ pmax,
                                               const int* __restrict__ cnt,
                                               const float* __restrict__ chW1, const float* __restrict__ chb1,
                                               const float* __restrict__ chW2, const float* __restrict__ chb2,
                                               const float* __restrict__ chW3, const float* __restrict__ chb3,
                                               const float* __restrict__ tW1, const float* __restrict__ tb1,
                                               const float* __restrict__ tW2, const float* __restrict__ tb2,
                                               const float* __restrict__ dW1, const float* __restrict__ db1,
                                               const float* __restrict__ dW2, const float* __restrict__ db2,
                                               float* __restrict__ out_ch, float* __restrict__ out_t,
                                               float* __restrict__ out_d) {
    int b = blockIdx.x, sec = blockIdx.y, t = threadIdx.x;
    __shared__ float g[2 * D];
    __shared__ float z1[D];
    __shared__ float z2[128];
    float sum = 0.f, mx = -3.0e38f;
#pragma unroll
    for (int sl = 0; sl < PS; sl++) {
        sum += psum[(size_t)(b * PS + sl) * D + t];
        mx = fmaxf(mx, pmax[(size_t)(b * PS + sl) * D + t]);
    }
    int cn = cnt[b];
    float c = fmaxf((float)cn, 1.f);
    g[t] = sum / c;
    g[D + t] = (cn > 0) ? mx : 0.f;
    __syncthreads();
    if (sec == 0) {
        z1[t] = fmaxf(chb1[t] + dot_ilp(g, chW1, 2 * D, D, t), 0.f);
        __syncthreads();
        if (t < 128) z2[t] = fmaxf(chb2[t] + dot_ilp(z1, chW2, D, 128, t), 0.f);
        __syncthreads();
        if (t < MC) out_ch[b * MC + t] = chb3[t] + dot_ilp(z2, chW3, 128, MC, t);
    } else if (sec == 1) {
        if (t < 128) z1[t] = fmaxf(tb1[t] + dot_ilp(g, tW1, 2 * D, 128, t), 0.f);
        __syncthreads();
        if (t < NT) out_t[b * NT + t] = tb2[t] + dot_ilp(z1, tW2, 128, NT, t);
    } else {
        if (t < 64) z1[t] = fmaxf(db1[t] + dot_ilp(g, dW1, 2 * D, 64, t), 0.f);
        __syncthreads();
        if (t == 0) {
            float a = db2[0] + dot_ilp(z1, dW2, 64, 1, 0);
            out_d[b] = 100.f / (1.f + __expf(-a));
        }
    }
}

// ----------------------------------------------------------------
extern "C" void kernel_launch(void* const* d_in, const int* in_sizes, int n_in,
                              void* d_out, int out_size, void* d_ws, size_t ws_size,
                              hipStream_t stream) {
    const float* x     = (const float*)d_in[0];
    const int*   ei    = (const int*)d_in[1];
    const int*   batch = (const int*)d_in[2];
    const float* encW  = (const float*)d_in[3];
    const float* encb  = (const float*)d_in[4];
    const float* encls = (const float*)d_in[5];
    const float* enclb = (const float*)d_in[6];
    const float* Wl    = (const float*)d_in[7];
    const float* bl    = (const float*)d_in[8];
    const float* Wr    = (const float*)d_in[9];
    const float* br    = (const float*)d_in[10];
    const float* att   = (const float*)d_in[11];
    const float* gb    = (const float*)d_in[12];
    const float* gls   = (const float*)d_in[13];
    const float* glb   = (const float*)d_in[14];
    const float* cW1   = (const float*)d_in[15];
    const float* cb1   = (const float*)d_in[16];
    const float* cW2   = (const float*)d_in[17];
    const float* cb2   = (const float*)d_in[18];
    const float* cW3   = (const float*)d_in[19];
    const float* cb3   = (const float*)d_in[20];
    const float* chW1  = (const float*)d_in[21];
    const float* chb1  = (const float*)d_in[22];
    const float* chW2  = (const float*)d_in[23];
    const float* chb2  = (const float*)d_in[24];
    const float* chW3  = (const float*)d_in[25];
    const float* chb3  = (const float*)d_in[26];
    const float* tW1   = (const float*)d_in[27];
    const float* tb1   = (const float*)d_in[28];
    const float* tW2   = (const float*)d_in[29];
    const float* tb2   = (const float*)d_in[30];
    const float* dW1   = (const float*)d_in[31];
    const float* db1   = (const float*)d_in[32];
    const float* dW2   = (const float*)d_in[33];
    const float* db2   = (const float*)d_in[34];

    const int N = in_sizes[0] / DIN;
    const int E = in_sizes[1] / 2;
    const int* esrc = ei;
    const int* edst = ei + E;

    char* p = (char*)d_ws;
    auto carve = [&](size_t bytes) { char* r = p; p += (bytes + 255) & ~(size_t)255; return r; };
    int*            row_ptr = (int*)carve((size_t)(N + 1) * 4);
    int*            fill    = (int*)carve((size_t)N * 4);
    int*            deg     = (int*)carve((size_t)N * 4);
    int*            cnt     = (int*)carve((size_t)BG * 4);
    float*          psum    = (float*)carve((size_t)BG * PS * D * 4);
    float*          pmax    = (float*)carve((size_t)BG * PS * D * 4);
    int*            col     = (int*)carve((size_t)(E + N) * 4);
    unsigned short* Wp      = (unsigned short*)carve((size_t)NL * 2 * 65536 * 2);
    unsigned short* cW1p    = (unsigned short*)carve((size_t)16 * 8 * 64 * 8 * 2);
    unsigned short* cW2p    = (unsigned short*)carve((size_t)8 * 8 * 64 * 8 * 2);
    unsigned short* cW3p    = (unsigned short*)carve((size_t)13 * 4 * 64 * 8 * 2);
    float*          h       = (float*)carve((size_t)N * D * 4);
    unsigned short* xlA     = (unsigned short*)carve((size_t)N * D * 2);
    unsigned short* xrA     = (unsigned short*)carve((size_t)N * D * 2);
    unsigned short* xlB     = (unsigned short*)carve((size_t)N * D * 2);
    unsigned short* xrB     = (unsigned short*)carve((size_t)N * D * 2);
    (void)ws_size; (void)n_in; (void)out_size;

    const int ntiles = (N + 15) / 16;
    const int sblocks = max(ntiles, (E + N + 255) / 256);

    // d1: deg init + encoder
    init_enc_k<<<(N + 3) / 4, 256, 0, stream>>>(x, encW, encb, encls, enclb, h, deg, N);
    // d2: count + repacks
    count_repack_k<<<512, 256, 0, stream>>>(edst, deg, E, Wl, Wr, Wp, cW1, cW1p, cW2, cW2p, cW3, cW3p);
    // d3: scan
    scan_k<<<1, 1024, 0, stream>>>(deg, row_ptr, fill, N);
    // d4: scatter + layer-0 gemm (writes parity-0 buffers)
    scatter_gemm0_k<<<sblocks, 256, 0, stream>>>(esrc, edst, fill, col, E, N, h,
                                                 Wp + 0, Wp + (size_t)65536,
                                                 bl + 0, br + 0, xlA, xrA);
    // d5..d9: fused attn_l + gemm_{l+1}
    for (int l = 0; l < NL - 1; l++) {
        const unsigned short* xin_l = (l & 1) ? xlB : xlA;
        const unsigned short* xin_r = (l & 1) ? xrB : xrA;
        unsigned short* xout_l = (l & 1) ? xlA : xlB;
        unsigned short* xout_r = (l & 1) ? xrA : xrB;
        layer_k<<<ntiles, 256, 0, stream>>>(xin_l, xin_r, row_ptr, col, att + l * NH * NC,
                                            gb + l * D, gls + l * D, glb + l * D, h, l, N,
                                            Wp + (size_t)((l + 1) * 2 + 0) * 65536,
                                            Wp + (size_t)((l + 1) * 2 + 1) * 65536,
                                            bl + (l + 1) * D, br + (l + 1) * D, xout_l, xout_r);
    }
    // d10: final attn + color head  (layer 5 parity: 5&1 = 1 -> B buffers)
    float* out = (float*)d_out;
    last_k<<<ntiles, 256, 0, stream>>>(xlB, xrB, row_ptr, col, att + (NL - 1) * NH * NC,
                                       gb + (NL - 1) * D, gls + (NL - 1) * D, glb + (NL - 1) * D, h, N,
                                       cW1p, cb1, cW2p, cb2, cW3p, cb3, out);
    // d11: pool
    pool_k<<<dim3(BG, PS), 256, 0, stream>>>(h, batch, psum, pmax, cnt, N);
    // d12: heads
    heads_k<<<dim3(BG, 3), 256, 0, stream>>>(psum, pmax, cnt, chW1, chb1, chW2, chb2, chW3, chb3,
                                             tW1, tb1, tW2, tb2, dW1, db1, dW2, db2,
                                             out + (size_t)N * MC,
                                             out + (size_t)N * MC + BG * MC,
                                             out + (size_t)N * MC + BG * MC + BG * NT);
}

// Round 12
// 441.280 us; speedup vs baseline: 5.1633x; 1.1980x over previous
//
#include <hip/hip_runtime.h>
#include <hip/hip_bf16.h>

constexpr int DIN = 16;
constexpr int D   = 256;
constexpr int NH  = 8;
constexpr int NC  = 32;
constexpr int MC  = 200;
constexpr int NT  = 8;
constexpr int BG  = 16;
constexpr int NL  = 6;
constexpr int PS  = 16;   // pool slices per graph
constexpr float NEG = 0.2f;

typedef __attribute__((ext_vector_type(8))) short bfrag;
typedef __attribute__((ext_vector_type(4))) float f32x4;

__device__ inline unsigned short f2bf(float f) {
    unsigned int u = __float_as_uint(f);
    u += 0x7FFFu + ((u >> 16) & 1u);
    return (unsigned short)(u >> 16);
}
__device__ inline float bf2f(unsigned short u) {
    return __uint_as_float((unsigned int)u << 16);
}

__device__ inline float dot_ilp(const float* g, const float* __restrict__ W, int K, int ldw, int t) {
    float a0 = 0.f, a1 = 0.f, a2 = 0.f, a3 = 0.f;
    for (int k = 0; k < K; k += 4) {
        a0 = fmaf(g[k + 0], W[(k + 0) * ldw + t], a0);
        a1 = fmaf(g[k + 1], W[(k + 1) * ldw + t], a1);
        a2 = fmaf(g[k + 2], W[(k + 2) * ldw + t], a2);
        a3 = fmaf(g[k + 3], W[(k + 3) * ldw + t], a3);
    }
    return (a0 + a1) + (a2 + a3);
}

// ---------------- device helpers ----------------

__device__ inline void enc_node(const float* x, const float* W, const float* b, const float* ls,
                                const float* lb, float* h, int n, int lane) {
    int c4 = lane * 4;
    float xs[DIN];
#pragma unroll
    for (int k = 0; k < DIN; k += 4) {
        float4 xv = *(const float4*)&x[n * DIN + k];
        xs[k] = xv.x; xs[k + 1] = xv.y; xs[k + 2] = xv.z; xs[k + 3] = xv.w;
    }
    float4 a = *(const float4*)&b[c4];
#pragma unroll
    for (int k = 0; k < DIN; k++) {
        float4 wv = *(const float4*)&W[k * D + c4];
        a.x = fmaf(xs[k], wv.x, a.x);
        a.y = fmaf(xs[k], wv.y, a.y);
        a.z = fmaf(xs[k], wv.z, a.z);
        a.w = fmaf(xs[k], wv.w, a.w);
    }
    float s = a.x + a.y + a.z + a.w;
#pragma unroll
    for (int msk = 1; msk <= 32; msk <<= 1) s += __shfl_xor(s, msk);
    float mu = s * (1.f / D);
    float4 dv = make_float4(a.x - mu, a.y - mu, a.z - mu, a.w - mu);
    float v2 = dv.x * dv.x + dv.y * dv.y + dv.z * dv.z + dv.w * dv.w;
#pragma unroll
    for (int msk = 1; msk <= 32; msk <<= 1) v2 += __shfl_xor(v2, msk);
    float rstd = rsqrtf(v2 * (1.f / D) + 1e-5f);
    float4 lsv = *(const float4*)&ls[c4];
    float4 lbv = *(const float4*)&lb[c4];
    float4 y = make_float4(fmaxf(dv.x * rstd * lsv.x + lbv.x, 0.f),
                           fmaxf(dv.y * rstd * lsv.y + lbv.y, 0.f),
                           fmaxf(dv.z * rstd * lsv.z + lbv.z, 0.f),
                           fmaxf(dv.w * rstd * lsv.w + lbv.w, 0.f));
    *(float4*)&h[(size_t)n * D + c4] = y;
}

// attn for one node (one full wave); returns residual-added output (4 channels of this lane)
__device__ inline float4 attn_compute(const unsigned short* xl, const unsigned short* xr,
                                      const int* row_ptr, const int* col, const float* att,
                                      const float* gb, const float* gls, const float* glb,
                                      const float* h, int layer, int n, int lane) {
    int c4 = lane * 4;
    ushort4 xr4 = *(const ushort4*)&xr[(size_t)n * D + c4];
    float4 xrv = make_float4(bf2f(xr4.x), bf2f(xr4.y), bf2f(xr4.z), bf2f(xr4.w));
    float4 av  = *(const float4*)&att[c4];
    int beg = row_ptr[n], end = row_ptr[n + 1];
    int deg = end - beg;
    int myc = col[beg + min(lane, deg - 1)];
    float m = -3.0e38f, l = 0.f;
    float4 acc = make_float4(0.f, 0.f, 0.f, 0.f);
    auto loadx = [&](int i) -> ushort4 {
        if (i < deg) {
            int s = (i < 64) ? __shfl(myc, i) : col[beg + i];
            return *(const ushort4*)&xl[(size_t)s * D + c4];
        }
        return make_ushort4(0, 0, 0, 0);
    };
    auto step = [&](ushort4 x4) {
        float4 xlv = make_float4(bf2f(x4.x), bf2f(x4.y), bf2f(x4.z), bf2f(x4.w));
        float sx = xlv.x + xrv.x; sx = sx > 0.f ? sx : NEG * sx;
        float sy = xlv.y + xrv.y; sy = sy > 0.f ? sy : NEG * sy;
        float sz = xlv.z + xrv.z; sz = sz > 0.f ? sz : NEG * sz;
        float sw = xlv.w + xrv.w; sw = sw > 0.f ? sw : NEG * sw;
        float z = av.x * sx + av.y * sy + av.z * sz + av.w * sw;
        z += __shfl_xor(z, 1); z += __shfl_xor(z, 2); z += __shfl_xor(z, 4);
        float mn = fmaxf(m, z);
        float sc = __expf(m - mn);
        float p  = __expf(z - mn);
        l = l * sc + p;
        acc.x = acc.x * sc + p * xlv.x;
        acc.y = acc.y * sc + p * xlv.y;
        acc.z = acc.z * sc + p * xlv.z;
        acc.w = acc.w * sc + p * xlv.w;
        m = mn;
    };
    ushort4 b0 = loadx(0), b1 = loadx(1), b2 = loadx(2), b3 = loadx(3);
    int e = 0;
    for (; e + 4 <= deg; e += 4) {
        ushort4 n0 = loadx(e + 4), n1 = loadx(e + 5), n2 = loadx(e + 6), n3 = loadx(e + 7);
        step(b0); step(b1); step(b2); step(b3);
        b0 = n0; b1 = n1; b2 = n2; b3 = n3;
    }
    if (e + 0 < deg) step(b0);
    if (e + 1 < deg) step(b1);
    if (e + 2 < deg) step(b2);
    float4 gbv = *(const float4*)&gb[c4];
    float rl = 1.f / l;
    float4 o = make_float4(acc.x * rl + gbv.x, acc.y * rl + gbv.y,
                           acc.z * rl + gbv.z, acc.w * rl + gbv.w);
    float s = o.x + o.y + o.z + o.w;
#pragma unroll
    for (int msk = 1; msk <= 32; msk <<= 1) s += __shfl_xor(s, msk);
    float mu = s * (1.f / D);
    float4 dv = make_float4(o.x - mu, o.y - mu, o.z - mu, o.w - mu);
    float v2 = dv.x * dv.x + dv.y * dv.y + dv.z * dv.z + dv.w * dv.w;
#pragma unroll
    for (int msk = 1; msk <= 32; msk <<= 1) v2 += __shfl_xor(v2, msk);
    float rstd = rsqrtf(v2 * (1.f / D) + 1e-5f);
    float4 glsv = *(const float4*)&gls[c4];
    float4 glbv = *(const float4*)&glb[c4];
    float y0 = dv.x * rstd * glsv.x + glbv.x;
    float y1 = dv.y * rstd * glsv.y + glbv.y;
    float y2 = dv.z * rstd * glsv.z + glbv.z;
    float y3 = dv.w * rstd * glsv.w + glbv.w;
    y0 = y0 > 0.f ? y0 : expm1f(y0);
    y1 = y1 > 0.f ? y1 : expm1f(y1);
    y2 = y2 > 0.f ? y2 : expm1f(y2);
    y3 = y3 > 0.f ? y3 : expm1f(y3);
    float4 prev = make_float4(0.f, 0.f, 0.f, 0.f);
    if (layer > 0) prev = *(const float4*)&h[(size_t)n * D + c4];
    return make_float4(prev.x + y0, prev.y + y1, prev.z + y2, prev.w + y3);
}

// MFMA GEMM on a 16-row tile, executed by ONE wave handling ONE 16-col tile (ctg).
__device__ inline void gemm_one_ct(const unsigned short (*As)[264],
                                   const unsigned short* WpL, const unsigned short* WpR,
                                   const float* bl, const float* br,
                                   unsigned short* xl, unsigned short* xr,
                                   int N, int nb, int ctg, int lane) {
    int m = lane & 15, q = lane >> 4;
    float bLv = bl[ctg * 16 + m];
    float bRv = br[ctg * 16 + m];
    f32x4 accL = (f32x4){bLv, bLv, bLv, bLv};
    f32x4 accR = (f32x4){bRv, bRv, bRv, bRv};
#pragma unroll
    for (int ks = 0; ks < 8; ks++) {
        bfrag af = *(const bfrag*)&As[m][ks * 32 + q * 8];
        size_t off = (((size_t)ctg * 8 + ks) * 64 + lane) * 8;
        bfrag bL = *(const bfrag*)&WpL[off];
        bfrag bR = *(const bfrag*)&WpR[off];
        accL = __builtin_amdgcn_mfma_f32_16x16x32_bf16(af, bL, accL, 0, 0, 0);
        accR = __builtin_amdgcn_mfma_f32_16x16x32_bf16(af, bR, accR, 0, 0, 0);
    }
    int colg = ctg * 16 + m;
#pragma unroll
    for (int reg = 0; reg < 4; reg++) {
        int row = nb + q * 4 + reg;
        if (row < N) {
            xl[(size_t)row * D + colg] = f2bf(accL[reg]);
            xr[(size_t)row * D + colg] = f2bf(accR[reg]);
        }
    }
}

// 4-wave variant (wave w owns col-tiles w*4..w*4+3) — used by scatter_gemm0_k
__device__ inline void gemm_core(const unsigned short (*As)[264],
                                 const unsigned short* WpL, const unsigned short* WpR,
                                 const float* bl, const float* br,
                                 unsigned short* xl, unsigned short* xr, int N, int nb, int T) {
    int lane = T & 63, w = T >> 6;
#pragma unroll
    for (int ct = 0; ct < 4; ct++)
        gemm_one_ct(As, WpL, WpR, bl, br, xl, xr, N, nb, w * 4 + ct, lane);
}

__device__ inline void repack_attn_one(const float* Wl, const float* Wr, unsigned short* Wp, int tid) {
    int lane = tid & 63;
    int r1 = tid >> 6;
    int ks = r1 & 7;
    int r2 = r1 >> 3;
    int ct = r2 & 15;
    int mi = r2 >> 4;
    int layer = mi >> 1, mat = mi & 1;
    const float* W = (mat == 0 ? Wl : Wr) + (size_t)layer * D * D;
    int n = ct * 16 + (lane & 15);
    int kb = ks * 32 + (lane >> 4) * 8;
    size_t base = (((size_t)(mi * 16 + ct) * 8 + ks) * 64 + lane) * 8;
#pragma unroll
    for (int j = 0; j < 8; j++) Wp[base + j] = f2bf(W[(size_t)(kb + j) * D + n]);
}

__device__ inline void repack_gen_one(const float* W, unsigned short* Wp, int K, int NCOL, int nks, int tid) {
    int lane = tid & 63;
    int r = tid >> 6;
    int ks = r % nks;
    int ct = r / nks;
    int n = ct * 16 + (lane & 15);
    int kb = ks * 32 + (lane >> 4) * 8;
    size_t base = (((size_t)ct * nks + ks) * 64 + lane) * 8;
#pragma unroll
    for (int j = 0; j < 8; j++) {
        int k = kb + j;
        Wp[base + j] = (n < NCOL && k < K) ? f2bf(W[(size_t)k * NCOL + n]) : (unsigned short)0;
    }
}

// ---------------- kernels (12 dispatches) ----------------

// d1: deg=1 + encoder (wave per node)
__global__ __launch_bounds__(256) void init_enc_k(const float* __restrict__ x, const float* __restrict__ W,
                                                  const float* __restrict__ b, const float* __restrict__ ls,
                                                  const float* __restrict__ lb, float* __restrict__ h,
                                                  int* __restrict__ deg, int N) {
    int gid = blockIdx.x * 256 + threadIdx.x;
    if (gid < N) deg[gid] = 1;
    int lane = threadIdx.x & 63;
    int n = blockIdx.x * 4 + (threadIdx.x >> 6);
    if (n < N) enc_node(x, W, b, ls, lb, h, n, lane);
}

// d2: edge count + all weight repacks
__global__ __launch_bounds__(256) void count_repack_k(const int* __restrict__ dst, int* __restrict__ deg, int E,
                                                      const float* __restrict__ Wl, const float* __restrict__ Wr,
                                                      unsigned short* __restrict__ Wp,
                                                      const float* __restrict__ cW1, unsigned short* __restrict__ cW1p,
                                                      const float* __restrict__ cW2, unsigned short* __restrict__ cW2p,
                                                      const float* __restrict__ cW3, unsigned short* __restrict__ cW3p) {
    int gid = blockIdx.x * 256 + threadIdx.x;
    if (gid < E) atomicAdd(&deg[dst[gid]], 1);
    if (gid < NL * 2 * 16 * 8 * 64) repack_attn_one(Wl, Wr, Wp, gid);
    if (gid < 16 * 8 * 64) repack_gen_one(cW1, cW1p, D, D, 8, gid);
    if (gid < 8 * 8 * 64)  repack_gen_one(cW2, cW2p, D, 128, 8, gid);
    if (gid < 13 * 4 * 64) repack_gen_one(cW3, cW3p, 128, MC, 4, gid);
}

// d3: single-block scan
__global__ __launch_bounds__(1024) void scan_k(const int* __restrict__ deg, int* __restrict__ row_ptr,
                                               int* __restrict__ fill, int N) {
    __shared__ int sd[1024];
    int t = threadIdx.x;
    int chunk = (N + 1023) >> 10;
    int lo = t * chunk, hi = min(lo + chunk, N);
    int s = 0;
    for (int i = lo; i < hi; i++) s += deg[i];
    sd[t] = s;
    __syncthreads();
    for (int off = 1; off < 1024; off <<= 1) {
        int v = (t >= off) ? sd[t - off] : 0;
        __syncthreads();
        sd[t] += v;
        __syncthreads();
    }
    int run = (t > 0) ? sd[t - 1] : 0;
    for (int i = lo; i < hi; i++) {
        row_ptr[i] = run; fill[i] = run;
        run += deg[i];
    }
    if (t == 1023) row_ptr[N] = sd[1023];
}

// d4: scatter + layer-0 GEMM
__global__ __launch_bounds__(256) void scatter_gemm0_k(const int* __restrict__ src, const int* __restrict__ dst,
                                                       int* __restrict__ fill, int* __restrict__ col, int E, int N,
                                                       const float* __restrict__ h,
                                                       const unsigned short* __restrict__ WpL,
                                                       const unsigned short* __restrict__ WpR,
                                                       const float* __restrict__ bl, const float* __restrict__ br,
                                                       unsigned short* __restrict__ xl, unsigned short* __restrict__ xr) {
    __shared__ unsigned short As[16][264];
    int T = threadIdx.x;
    int tt = blockIdx.x;
    int ntiles = (N + 15) >> 4;
    if (tt < ntiles) {
        int nb = tt * 16;
#pragma unroll
        for (int r = 0; r < 16; r++) {
            int row = nb + r;
            float v = (row < N) ? h[(size_t)row * D + T] : 0.f;
            As[r][T] = f2bf(v);
        }
        __syncthreads();
        gemm_core(As, WpL, WpR, bl, br, xl, xr, N, nb, T);
    }
    for (int e = blockIdx.x * 256 + T; e < E + N; e += gridDim.x * 256) {
        if (e < E) {
            int p = atomicAdd(&fill[dst[e]], 1);
            col[p] = src[e];
        } else {
            int n = e - E;
            int p = atomicAdd(&fill[n], 1);
            col[p] = n;
        }
    }
}

// d5..d9: fused attn(l) + gemm(l+1). 1024 threads = 16 waves; ONE WAVE PER NODE for attn,
// then each wave owns one 16-col tile of the 16-row MFMA GEMM.
__global__ __launch_bounds__(1024) void layer_k(const unsigned short* __restrict__ xl_in,
                                                const unsigned short* __restrict__ xr_in,
                                                const int* __restrict__ row_ptr, const int* __restrict__ col,
                                                const float* __restrict__ att, const float* __restrict__ gb,
                                                const float* __restrict__ gls, const float* __restrict__ glb,
                                                float* __restrict__ h, int layer, int N,
                                                const unsigned short* __restrict__ WpL,
                                                const unsigned short* __restrict__ WpR,
                                                const float* __restrict__ bl, const float* __restrict__ br,
                                                unsigned short* __restrict__ xl_out, unsigned short* __restrict__ xr_out) {
    __shared__ unsigned short As[16][264];
    int T = threadIdx.x;
    int lane = T & 63, wv = T >> 6;       // wv in [0,16)
    int nb = blockIdx.x * 16;
    int c4 = lane * 4;
    int n = nb + wv;
    if (n < N) {
        float4 res = attn_compute(xl_in, xr_in, row_ptr, col, att, gb, gls, glb, h, layer, n, lane);
        *(float4*)&h[(size_t)n * D + c4] = res;
        As[wv][c4 + 0] = f2bf(res.x);
        As[wv][c4 + 1] = f2bf(res.y);
        As[wv][c4 + 2] = f2bf(res.z);
        As[wv][c4 + 3] = f2bf(res.w);
    } else {
        As[wv][c4 + 0] = 0; As[wv][c4 + 1] = 0; As[wv][c4 + 2] = 0; As[wv][c4 + 3] = 0;
    }
    __syncthreads();
    gemm_one_ct(As, WpL, WpR, bl, br, xl_out, xr_out, N, nb, wv, lane);
}

// d10: final attn (layer 5) + fused color-head MFMA MLP (1024 threads, wave per node)
__global__ __launch_bounds__(1024) void last_k(const unsigned short* __restrict__ xl_in,
                                               const unsigned short* __restrict__ xr_in,
                                               const int* __restrict__ row_ptr, const int* __restrict__ col,
                                               const float* __restrict__ att, const float* __restrict__ gb,
                                               const float* __restrict__ gls, const float* __restrict__ glb,
                                               float* __restrict__ h, int N,
                                               const unsigned short* __restrict__ W1p, const float* __restrict__ b1,
                                               const unsigned short* __restrict__ W2p, const float* __restrict__ b2,
                                               const unsigned short* __restrict__ W3p, const float* __restrict__ b3,
                                               float* __restrict__ out) {
    __shared__ unsigned short As[16][264];
    __shared__ unsigned short Zs[16][264];
    int T = threadIdx.x;
    int lane = T & 63, wv = T >> 6;
    int nb = blockIdx.x * 16;
    int c4 = lane * 4;
    int n = nb + wv;
    if (n < N) {
        float4 res = attn_compute(xl_in, xr_in, row_ptr, col, att, gb, gls, glb, h, NL - 1, n, lane);
        *(float4*)&h[(size_t)n * D + c4] = res;
        As[wv][c4 + 0] = f2bf(res.x);
        As[wv][c4 + 1] = f2bf(res.y);
        As[wv][c4 + 2] = f2bf(res.z);
        As[wv][c4 + 3] = f2bf(res.w);
    } else {
        As[wv][c4 + 0] = 0; As[wv][c4 + 1] = 0; As[wv][c4 + 2] = 0; As[wv][c4 + 3] = 0;
    }
    __syncthreads();
    int m = lane & 15, q = lane >> 4;
    // layer1: 256->256, wave wv owns col-tile wv
    {
        float bv = b1[wv * 16 + m];
        f32x4 acc = (f32x4){bv, bv, bv, bv};
#pragma unroll
        for (int ks = 0; ks < 8; ks++) {
            bfrag af = *(const bfrag*)&As[m][ks * 32 + q * 8];
            bfrag bf = *(const bfrag*)&W1p[(((size_t)wv * 8 + ks) * 64 + lane) * 8];
            acc = __builtin_amdgcn_mfma_f32_16x16x32_bf16(af, bf, acc, 0, 0, 0);
        }
        int colg = wv * 16 + m;
#pragma unroll
        for (int reg = 0; reg < 4; reg++)
            Zs[q * 4 + reg][colg] = f2bf(fmaxf(acc[reg], 0.f));
    }
    __syncthreads();
    // layer2: 256->128, waves 0..7 own col-tiles 0..7; result back into As cols 0..127
    if (wv < 8) {
        float bv = b2[wv * 16 + m];
        f32x4 acc = (f32x4){bv, bv, bv, bv};
#pragma unroll
        for (int ks = 0; ks < 8; ks++) {
            bfrag af = *(const bfrag*)&Zs[m][ks * 32 + q * 8];
            bfrag bf = *(const bfrag*)&W2p[(((size_t)wv * 8 + ks) * 64 + lane) * 8];
            acc = __builtin_amdgcn_mfma_f32_16x16x32_bf16(af, bf, acc, 0, 0, 0);
        }
        int colg = wv * 16 + m;
#pragma unroll
        for (int reg = 0; reg < 4; reg++)
            As[q * 4 + reg][colg] = f2bf(fmaxf(acc[reg], 0.f));
    }
    __syncthreads();
    // layer3: 128->200 (13 col-tiles), waves 0..12
    if (wv < 13) {
        int colg = wv * 16 + m;
        float bv = (colg < MC) ? b3[colg] : 0.f;
        f32x4 acc = (f32x4){bv, bv, bv, bv};
#pragma unroll
        for (int ks = 0; ks < 4; ks++) {
            bfrag af = *(const bfrag*)&As[m][ks * 32 + q * 8];
            bfrag bf = *(const bfrag*)&W3p[(((size_t)wv * 4 + ks) * 64 + lane) * 8];
            acc = __builtin_amdgcn_mfma_f32_16x16x32_bf16(af, bf, acc, 0, 0, 0);
        }
#pragma unroll
        for (int reg = 0; reg < 4; reg++) {
            int row = nb + q * 4 + reg;
            if (row < N && colg < MC) out[(size_t)row * MC + colg] = acc[reg];
        }
    }
}

// d11: pooling stage 1
__global__ __launch_bounds__(256) void pool_k(const float* __restrict__ h, const int* __restrict__ batch,
                                              float* __restrict__ psum, float* __restrict__ pmax,
                                              int* __restrict__ cnt, int N) {
    int b = blockIdx.x;
    int sl = blockIdx.y;
    int c = threadIdx.x;
    int lo = 0, hi = N;
    while (lo < hi) { int mid = (lo + hi) >> 1; if (batch[mid] < b) lo = mid + 1; else hi = mid; }
    int s0 = lo;
    lo = 0; hi = N;
    while (lo < hi) { int mid = (lo + hi) >> 1; if (batch[mid] < b + 1) lo = mid + 1; else hi = mid; }
    int s1 = lo;
    int len = s1 - s0;
    int chunk = (len + PS - 1) / PS;
    int n0 = s0 + sl * chunk;
    int n1 = min(n0 + chunk, s1);
    float sum = 0.f, mx = -3.0e38f;
    for (int n = n0; n < n1; n++) {
        float v = h[(size_t)n * D + c];
        sum += v;
        mx = fmaxf(mx, v);
    }
    psum[(size_t)(b * PS + sl) * D + c] = sum;
    pmax[(size_t)(b * PS + sl) * D + c] = mx;
    if (c == 0 && sl == 0) cnt[b] = len;
}

// d12: graph heads
__global__ __launch_bounds__(256) void heads_k(const float* __restrict__ psum, const float* __restrict__ pmax,
                                               const int* __restrict__ cnt,
                                               const float* __restrict__ chW1, const float* __restrict__ chb1,
                                               const float* __restrict__ chW2, const float* __restrict__ chb2,
                                               const float* __restrict__ chW3, const float* __restrict__ chb3,
                                               const float* __restrict__ tW1, const float* __restrict__ tb1,
                                               const float* __restrict__ tW2, const float* __restrict__ tb2,
                                               const float* __restrict__ dW1, const float* __restrict__ db1,
                                               const float* __restrict__ dW2, const float* __restrict__ db2,
                                               float* __restrict__ out_ch, float* __restrict__ out_t,
                                               float* __restrict__ out_d) {
    int b = blockIdx.x, sec = blockIdx.y, t = threadIdx.x;
    __shared__ float g[2 * D];
    __shared__ float z1[D];
    __shared__ float z2[128];
    float sum = 0.f, mx = -3.0e38f;
#pragma unroll
    for (int sl = 0; sl < PS; sl++) {
        sum += psum[(size_t)(b * PS + sl) * D + t];
        mx = fmaxf(mx, pmax[(size_t)(b * PS + sl) * D + t]);
    }
    int cn = cnt[b];
    float c = fmaxf((float)cn, 1.f);
    g[t] = sum / c;
    g[D + t] = (cn > 0) ? mx : 0.f;
    __syncthreads();
    if (sec == 0) {
        z1[t] = fmaxf(chb1[t] + dot_ilp(g, chW1, 2 * D, D, t), 0.f);
        __syncthreads();
        if (t < 128) z2[t] = fmaxf(chb2[t] + dot_ilp(z1, chW2, D, 128, t), 0.f);
        __syncthreads();
        if (t < MC) out_ch[b * MC + t] = chb3[t] + dot_ilp(z2, chW3, 128, MC, t);
    } else if (sec == 1) {
        if (t < 128) z1[t] = fmaxf(tb1[t] + dot_ilp(g, tW1, 2 * D, 128, t), 0.f);
        __syncthreads();
        if (t < NT) out_t[b * NT + t] = tb2[t] + dot_ilp(z1, tW2, 128, NT, t);
    } else {
        if (t < 64) z1[t] = fmaxf(db1[t] + dot_ilp(g, dW1, 2 * D, 64, t), 0.f);
        __syncthreads();
        if (t == 0) {
            float a = db2[0] + dot_ilp(z1, dW2, 64, 1, 0);
            out_d[b] = 100.f / (1.f + __expf(-a));
        }
    }
}

// ----------------------------------------------------------------
extern "C" void kernel_launch(void* const* d_in, const int* in_sizes, int n_in,
                              void* d_out, int out_size, void* d_ws, size_t ws_size,
                              hipStream_t stream) {
    const float* x     = (const float*)d_in[0];
    const int*   ei    = (const int*)d_in[1];
    const int*   batch = (const int*)d_in[2];
    const float* encW  = (const float*)d_in[3];
    const float* encb  = (const float*)d_in[4];
    const float* encls = (const float*)d_in[5];
    const float* enclb = (const float*)d_in[6];
    const float* Wl    = (const float*)d_in[7];
    const float* bl    = (const float*)d_in[8];
    const float* Wr    = (const float*)d_in[9];
    const float* br    = (const float*)d_in[10];
    const float* att   = (const float*)d_in[11];
    const float* gb    = (const float*)d_in[12];
    const float* gls   = (const float*)d_in[13];
    const float* glb   = (const float*)d_in[14];
    const float* cW1   = (const float*)d_in[15];
    const float* cb1   = (const float*)d_in[16];
    const float* cW2   = (const float*)d_in[17];
    const float* cb2   = (const float*)d_in[18];
    const float* cW3   = (const float*)d_in[19];
    const float* cb3   = (const float*)d_in[20];
    const float* chW1  = (const float*)d_in[21];
    const float* chb1  = (const float*)d_in[22];
    const float* chW2  = (const float*)d_in[23];
    const float* chb2  = (const float*)d_in[24];
    const float* chW3  = (const float*)d_in[25];
    const float* chb3  = (const float*)d_in[26];
    const float* tW1   = (const float*)d_in[27];
    const float* tb1   = (const float*)d_in[28];
    const float* tW2   = (const float*)d_in[29];
    const float* tb2   = (const float*)d_in[30];
    const float* dW1   = (const float*)d_in[31];
    const float* db1   = (const float*)d_in[32];
    const float* dW2   = (const float*)d_in[33];
    const float* db2   = (const float*)d_in[34];

    const int N = in_sizes[0] / DIN;
    const int E = in_sizes[1] / 2;
    const int* esrc = ei;
    const int* edst = ei + E;

    char* p = (char*)d_ws;
    auto carve = [&](size_t bytes) { char* r = p; p += (bytes + 255) & ~(size_t)255; return r; };
    int*            row_ptr = (int*)carve((size_t)(N + 1) * 4);
    int*            fill    = (int*)carve((size_t)N * 4);
    int*            deg     = (int*)carve((size_t)N * 4);
    int*            cnt     = (int*)carve((size_t)BG * 4);
    float*          psum    = (float*)carve((size_t)BG * PS * D * 4);
    float*          pmax    = (float*)carve((size_t)BG * PS * D * 4);
    int*            col     = (int*)carve((size_t)(E + N) * 4);
    unsigned short* Wp      = (unsigned short*)carve((size_t)NL * 2 * 65536 * 2);
    unsigned short* cW1p    = (unsigned short*)carve((size_t)16 * 8 * 64 * 8 * 2);
    unsigned short* cW2p    = (unsigned short*)carve((size_t)8 * 8 * 64 * 8 * 2);
    unsigned short* cW3p    = (unsigned short*)carve((size_t)13 * 4 * 64 * 8 * 2);
    float*          h       = (float*)carve((size_t)N * D * 4);
    unsigned short* xlA     = (unsigned short*)carve((size_t)N * D * 2);
    unsigned short* xrA     = (unsigned short*)carve((size_t)N * D * 2);
    unsigned short* xlB     = (unsigned short*)carve((size_t)N * D * 2);
    unsigned short* xrB     = (unsigned short*)carve((size_t)N * D * 2);
    (void)ws_size; (void)n_in; (void)out_size;

    const int ntiles = (N + 15) / 16;
    const int sblocks = max(ntiles, (E + N + 255) / 256);

    init_enc_k<<<(N + 3) / 4, 256, 0, stream>>>(x, encW, encb, encls, enclb, h, deg, N);
    count_repack_k<<<512, 256, 0, stream>>>(edst, deg, E, Wl, Wr, Wp, cW1, cW1p, cW2, cW2p, cW3, cW3p);
    scan_k<<<1, 1024, 0, stream>>>(deg, row_ptr, fill, N);
    scatter_gemm0_k<<<sblocks, 256, 0, stream>>>(esrc, edst, fill, col, E, N, h,
                                                 Wp + 0, Wp + (size_t)65536,
                                                 bl + 0, br + 0, xlA, xrA);
    for (int l = 0; l < NL - 1; l++) {
        const unsigned short* xin_l = (l & 1) ? xlB : xlA;
        const unsigned short* xin_r = (l & 1) ? xrB : xrA;
        unsigned short* xout_l = (l & 1) ? xlA : xlB;
        unsigned short* xout_r = (l & 1) ? xrA : xrB;
        layer_k<<<ntiles, 1024, 0, stream>>>(xin_l, xin_r, row_ptr, col, att + l * NH * NC,
                                             gb + l * D, gls + l * D, glb + l * D, h, l, N,
                                             Wp + (size_t)((l + 1) * 2 + 0) * 65536,
                                             Wp + (size_t)((l + 1) * 2 + 1) * 65536,
                                             bl + (l + 1) * D, br + (l + 1) * D, xout_l, xout_r);
    }
    float* out = (float*)d_out;
    last_k<<<ntiles, 1024, 0, stream>>>(xlB, xrB, row_ptr, col, att + (NL - 1) * NH * NC,
                                        gb + (NL - 1) * D, gls + (NL - 1) * D, glb + (NL - 1) * D, h, N,
                                        cW1p, cb1, cW2p, cb2, cW3p, cb3, out);
    pool_k<<<dim3(BG, PS), 256, 0, stream>>>(h, batch, psum, pmax, cnt, N);
    heads_k<<<dim3(BG, 3), 256, 0, stream>>>(psum, pmax, cnt, chW1, chb1, chW2, chb2, chW3, chb3,
                                             tW1, tb1, tW2, tb2, dW1, db1, dW2, db2,
                                             out + (size_t)N * MC,
                                             out + (size_t)N * MC + BG * MC,
                                             out + (size_t)N * MC + BG * MC + BG * NT);
}